// Round 1
// baseline (2237.722 us; speedup 1.0000x reference)
//
#include <hip/hip_runtime.h>
#include <hip/hip_bf16.h>
#include <cmath>

// Problem constants (BasicRecurrentLayer): B=64, T=1024, F=128, U=256
constexpr int B = 64;
constexpr int T = 1024;
constexpr int F = 128;
constexpr int U = 256;
constexpr int BT = 64;   // t-rows per projection workgroup

// ---------------------------------------------------------------------------
// h storage type helpers (fp32 if workspace fits 64 MB, else bf16 = 32 MB)
// ---------------------------------------------------------------------------
__device__ __forceinline__ float toF32(float v) { return v; }
__device__ __forceinline__ float toF32(__hip_bfloat16 v) { return __bfloat162float(v); }
__device__ __forceinline__ void storeH(float* p, float v) { *p = v; }
__device__ __forceinline__ void storeH(__hip_bfloat16* p, float v) { *p = __float2bfloat16(v); }

// ---------------------------------------------------------------------------
// Kernel 1: projection  h[t, b, u] = sum_f inputs[b, t, f] * R[f, u]
// Grid: (B, T/BT) blocks of 256 threads. Thread u holds R[:,u] in 128 VGPRs;
// the 64x128 input tile is staged in LDS (32 KB) and broadcast-read.
// ---------------------------------------------------------------------------
template <typename HT>
__global__ __launch_bounds__(256, 2) void proj_kernel(
    const float* __restrict__ in,   // [B, T, F]
    const float* __restrict__ Rm,   // [F, U]
    HT* __restrict__ h)             // [T, B, U]
{
    const int b  = blockIdx.x;
    const int t0 = blockIdx.y * BT;
    const int u  = threadIdx.x;

    __shared__ __align__(16) float a_lds[BT * F];   // 32 KB

    // Stage the contiguous 64x128 input tile (rows t0..t0+63 of batch b).
    const float4* src = (const float4*)(in + ((size_t)b * T + t0) * F);
    float4* dst = (float4*)a_lds;
    #pragma unroll
    for (int i = 0; i < (BT * F / 4) / 256; ++i) {
        dst[threadIdx.x + i * 256] = src[threadIdx.x + i * 256];
    }

    // Per-thread R column (coalesced across u for each f).
    float rcol[F];
    #pragma unroll
    for (int k = 0; k < F; ++k) rcol[k] = Rm[(size_t)k * U + u];

    __syncthreads();

    for (int r = 0; r < BT; ++r) {
        float acc0 = 0.f, acc1 = 0.f, acc2 = 0.f, acc3 = 0.f;
        #pragma unroll
        for (int kq = 0; kq < F / 4; ++kq) {
            float4 av = *((const float4*)(a_lds + r * F + kq * 4));
            acc0 = fmaf(av.x, rcol[kq * 4 + 0], acc0);
            acc1 = fmaf(av.y, rcol[kq * 4 + 1], acc1);
            acc2 = fmaf(av.z, rcol[kq * 4 + 2], acc2);
            acc3 = fmaf(av.w, rcol[kq * 4 + 3], acc3);
        }
        storeH(&h[((size_t)(t0 + r) * B + b) * U + u], acc0 + acc1 + acc2 + acc3);
    }
}

// ---------------------------------------------------------------------------
// Kernel 2: recurrence. One workgroup per batch row b (64 WGs, 256 threads).
// Thread u holds W[:,u] in 256 VGPRs (launch_bounds(256,1) -> 512 VGPR cap).
// State (256 floats) lives in LDS; each step: 64 broadcast ds_read_b128 +
// 256 FMAs (4 accumulators), tanh, coalesced store, 2 barriers.
// ---------------------------------------------------------------------------
template <typename HT>
__global__ __launch_bounds__(256, 1) void rnn_kernel(
    const HT* __restrict__ h,        // [T, B, U]
    const float* __restrict__ Wm,    // [U, U]
    const float* __restrict__ bias,  // [U]
    const float* __restrict__ x0,    // [U]
    float* __restrict__ out)         // [T, B, U]
{
    const int b = blockIdx.x;
    const int u = threadIdx.x;

    // W column u into registers (coalesced: consecutive u -> contiguous).
    float w[U];
    #pragma unroll
    for (int k = 0; k < U; ++k) w[k] = Wm[(size_t)k * U + u];

    const float bi = bias[u];

    __shared__ __align__(16) float s_lds[U];
    s_lds[u] = x0[u];

    const size_t stepStride = (size_t)B * U;
    const HT* hp = h + (size_t)b * U + u;       // h[t=0, b, u]
    float* op = out + (size_t)b * U + u;        // out[t=0, b, u]

    float hv = toF32(hp[0]);                    // h for t=0
    __syncthreads();

    for (int t = 0; t < T; ++t) {
        // Prefetch next step's h early so it is in flight during the FMAs.
        float hnext = 0.f;
        if (t + 1 < T) hnext = toF32(hp[(size_t)(t + 1) * stepStride]);

        float acc0 = 0.f, acc1 = 0.f, acc2 = 0.f, acc3 = 0.f;
        #pragma unroll
        for (int kq = 0; kq < U / 4; ++kq) {
            float4 sv = *((const float4*)(s_lds + kq * 4));   // broadcast read
            acc0 = fmaf(sv.x, w[kq * 4 + 0], acc0);
            acc1 = fmaf(sv.y, w[kq * 4 + 1], acc1);
            acc2 = fmaf(sv.z, w[kq * 4 + 2], acc2);
            acc3 = fmaf(sv.w, w[kq * 4 + 3], acc3);
        }

        const float val = tanhf((acc0 + acc1) + (acc2 + acc3) + hv + bi);
        op[(size_t)t * stepStride] = val;

        __syncthreads();          // everyone done reading s_lds for step t
        s_lds[u] = val;
        hv = hnext;
        __syncthreads();          // new state visible
    }
}

// ---------------------------------------------------------------------------
extern "C" void kernel_launch(void* const* d_in, const int* in_sizes, int n_in,
                              void* d_out, int out_size, void* d_ws, size_t ws_size,
                              hipStream_t stream) {
    const float* in   = (const float*)d_in[0];  // [B, T, F]
    const float* Rm   = (const float*)d_in[1];  // [F, U]
    const float* Wm   = (const float*)d_in[2];  // [U, U]
    const float* bias = (const float*)d_in[3];  // [U]
    const float* x0   = (const float*)d_in[4];  // [U]
    float* out = (float*)d_out;                 // [T, B, U]

    const size_t hElems = (size_t)T * B * U;

    if (ws_size >= hElems * sizeof(float)) {
        float* h = (float*)d_ws;
        proj_kernel<float><<<dim3(B, T / BT), 256, 0, stream>>>(in, Rm, h);
        rnn_kernel<float><<<dim3(B), 256, 0, stream>>>(h, Wm, bias, x0, out);
    } else {
        __hip_bfloat16* h = (__hip_bfloat16*)d_ws;
        proj_kernel<__hip_bfloat16><<<dim3(B, T / BT), 256, 0, stream>>>(in, Rm, h);
        rnn_kernel<__hip_bfloat16><<<dim3(B), 256, 0, stream>>>(h, Wm, bias, x0, out);
    }
}

// Round 2
// 1292.211 us; speedup vs baseline: 1.7317x; 1.7317x over previous
//
#include <hip/hip_runtime.h>
#include <hip/hip_bf16.h>
#include <cmath>

// Problem constants (BasicRecurrentLayer): B=64, T=1024, F=128, U=256
constexpr int B = 64;
constexpr int T = 1024;
constexpr int F = 128;
constexpr int U = 256;
constexpr int CH = 8;       // rnn: steps per h-prefetch/out-flush chunk

// ---------------------------------------------------------------------------
// h storage helpers (fp32 if workspace fits 64 MB, else bf16 = 32 MB)
// ---------------------------------------------------------------------------
__device__ __forceinline__ float toF32(float v) { return v; }
__device__ __forceinline__ float toF32(__hip_bfloat16 v) { return __bfloat162float(v); }

__device__ __forceinline__ void store8(float* p, const float* a) {
    ((float4*)p)[0] = make_float4(a[0], a[1], a[2], a[3]);
    ((float4*)p)[1] = make_float4(a[4], a[5], a[6], a[7]);
}
__device__ __forceinline__ void store8(__hip_bfloat16* p, const float* a) {
    unsigned int v[4];
    #pragma unroll
    for (int i = 0; i < 4; ++i) {
        __hip_bfloat16 lo = __float2bfloat16(a[2 * i]);
        __hip_bfloat16 hi = __float2bfloat16(a[2 * i + 1]);
        unsigned short lob = *(unsigned short*)&lo;
        unsigned short hib = *(unsigned short*)&hi;
        v[i] = (unsigned int)lob | ((unsigned int)hib << 16);
    }
    ((uint4*)p)[0] = make_uint4(v[0], v[1], v[2], v[3]);
}

__device__ __forceinline__ float rdlane(float v, int l) {
    return __uint_as_float(__builtin_amdgcn_readlane(__float_as_uint(v), l));
}

// ---------------------------------------------------------------------------
// Kernel 1: projection  h[t, b, u] = sum_f inputs[b, t, f] * R[f, u]
// Grid (T/64, U/64, B), 512 threads (8 waves). lane = t-row r; wave owns 8 u.
// A-tile (64x128 fp32, 32 KB) in LDS with XOR-swizzled float4 slots:
// slot(r,k4) at r*32 + (k4 ^ (r&31))  -> conflict-free b128 read AND write.
// R is read with wave-uniform addresses -> scalar loads -> SGPR fma operand.
// ---------------------------------------------------------------------------
template <typename HT>
__global__ __launch_bounds__(512, 2) void proj_kernel(
    const float* __restrict__ in,   // [B, T, F]
    const float* __restrict__ Rm,   // [F, U]
    HT* __restrict__ h)             // [T, B, U]
{
    const int t0   = blockIdx.x * 64;
    const int u0b  = blockIdx.y * 64;
    const int b    = blockIdx.z;
    const int tid  = threadIdx.x;
    const int lane = tid & 63;      // = r (t-row within tile)
    const int wv   = tid >> 6;      // 0..7
    // wave-uniform u base (forced into SGPR so R loads become scalar loads)
    const int u0   = __builtin_amdgcn_readfirstlane(u0b + wv * 8);

    __shared__ float4 a4[64 * 32];  // 32 KB, swizzled

    // Stage the contiguous 64x128 tile (rows t0..t0+63 of batch b): 2048 float4.
    const float4* src = (const float4*)(in + ((size_t)b * T + t0) * F);
    #pragma unroll
    for (int it = 0; it < 4; ++it) {
        int f  = tid + it * 512;        // 0..2047 (coalesced global read)
        int r  = f >> 5;
        int k4 = f & 31;
        a4[(r << 5) | (k4 ^ (r & 31))] = src[f];
    }
    __syncthreads();

    float acc[8];
    #pragma unroll
    for (int j = 0; j < 8; ++j) acc[j] = 0.f;

    const int r = lane;
    for (int k4 = 0; k4 < 32; ++k4) {
        float4 av = a4[(r << 5) | (k4 ^ (r & 31))];   // conflict-free b128
        const float* R0 = Rm + (size_t)(k4 * 4 + 0) * U + u0;
        const float* R1 = Rm + (size_t)(k4 * 4 + 1) * U + u0;
        const float* R2 = Rm + (size_t)(k4 * 4 + 2) * U + u0;
        const float* R3 = Rm + (size_t)(k4 * 4 + 3) * U + u0;
        #pragma unroll
        for (int j = 0; j < 8; ++j) {
            acc[j] = fmaf(av.x, R0[j], acc[j]);
            acc[j] = fmaf(av.y, R1[j], acc[j]);
            acc[j] = fmaf(av.z, R2[j], acc[j]);
            acc[j] = fmaf(av.w, R3[j], acc[j]);
        }
    }

    HT* hp = h + ((size_t)(t0 + r) * B + b) * U + u0;
    store8(hp, acc);
}

// ---------------------------------------------------------------------------
// Kernel 2: recurrence. Grid 64 (one WG per batch row), 512 threads = 8 waves.
// Wave wv: kh = wv&1 (k-half), ug = wv>>1 (u-group of 64). Each thread:
//   - 128 W values in VGPRs (fits: no spill)
//   - state half distributed across lanes: s0 = s[k0+lane], s1 = s[k0+64+lane]
//   - per step: 128 x (v_readlane -> SGPR, v_fma with SGPR operand)
// Partials exchanged via 1 LDS slot; new state broadcast via 256 B of LDS.
// h prefetch + out stores chunked (CH=8) so vmcnt drains hit 1 barrier per
// chunk instead of every step.
// ---------------------------------------------------------------------------
template <typename HT>
__global__ __launch_bounds__(512, 1) void rnn_kernel(
    const HT* __restrict__ h,        // [T, B, U]
    const float* __restrict__ Wm,    // [U, U]
    const float* __restrict__ bias,  // [U]
    const float* __restrict__ x0,    // [U]
    float* __restrict__ out)         // [T, B, U]
{
    const int b    = blockIdx.x;
    const int tid  = threadIdx.x;
    const int lane = tid & 63;
    const int wv   = tid >> 6;       // 0..7
    const int kh   = wv & 1;         // k-half
    const int ug   = wv >> 1;        // u-group
    const int u    = (ug << 6) | lane;
    const int k0   = kh << 7;        // 0 or 128

    // W column-half into registers (coalesced across lanes for each j).
    float w[128];
    #pragma unroll
    for (int j = 0; j < 128; ++j) w[j] = Wm[(size_t)(k0 + j) * U + u];

    __shared__ float s_lds[U];       // new-state staging
    __shared__ float p_lds[U];       // kh=1 partials

    // Initial state (t=0), distributed: lane l holds s[k0+l], s[k0+64+l].
    float s0 = x0[k0 + lane];
    float s1 = x0[k0 + 64 + lane];

    const float bi = bias[u];
    const size_t sT = (size_t)B * U;
    const HT* hp = h + (size_t)b * U + u;
    float* op = out + (size_t)b * U + u;

    float hc[CH], hn[CH], ob[CH];
    if (kh == 0) {
        #pragma unroll
        for (int i = 0; i < CH; ++i) hc[i] = toF32(hp[(size_t)i * sT]);
    }

    for (int tc = 0; tc < T; tc += CH) {
        if (kh == 0) {
            if (tc + CH < T) {
                #pragma unroll
                for (int i = 0; i < CH; ++i)
                    hn[i] = toF32(hp[(size_t)(tc + CH + i) * sT]);
            }
            if (tc > 0) {
                #pragma unroll
                for (int i = 0; i < CH; ++i)
                    op[(size_t)(tc - CH + i) * sT] = ob[i];
            }
        }

        #pragma unroll
        for (int i = 0; i < CH; ++i) {
            float a0 = 0.f, a1 = 0.f, a2 = 0.f, a3 = 0.f;
            #pragma unroll
            for (int k = 0; k < 64; k += 4) {
                a0 = fmaf(rdlane(s0, k + 0), w[k + 0], a0);
                a1 = fmaf(rdlane(s0, k + 1), w[k + 1], a1);
                a2 = fmaf(rdlane(s0, k + 2), w[k + 2], a2);
                a3 = fmaf(rdlane(s0, k + 3), w[k + 3], a3);
            }
            #pragma unroll
            for (int k = 0; k < 64; k += 4) {
                a0 = fmaf(rdlane(s1, k + 0), w[64 + k + 0], a0);
                a1 = fmaf(rdlane(s1, k + 1), w[64 + k + 1], a1);
                a2 = fmaf(rdlane(s1, k + 2), w[64 + k + 2], a2);
                a3 = fmaf(rdlane(s1, k + 3), w[64 + k + 3], a3);
            }
            float part = (a0 + a1) + (a2 + a3);
            if (kh == 1) p_lds[u] = part;
            __syncthreads();
            if (kh == 0) {
                float val = tanhf(part + p_lds[u] + hc[i] + bi);
                ob[i] = val;
                s_lds[u] = val;
            }
            __syncthreads();
            s0 = s_lds[k0 + lane];
            s1 = s_lds[k0 + 64 + lane];
        }

        if (kh == 0 && tc + CH < T) {
            #pragma unroll
            for (int i = 0; i < CH; ++i) hc[i] = hn[i];
        }
    }

    if (kh == 0) {
        #pragma unroll
        for (int i = 0; i < CH; ++i)
            op[(size_t)(T - CH + i) * sT] = ob[i];
    }
}

// ---------------------------------------------------------------------------
extern "C" void kernel_launch(void* const* d_in, const int* in_sizes, int n_in,
                              void* d_out, int out_size, void* d_ws, size_t ws_size,
                              hipStream_t stream) {
    const float* in   = (const float*)d_in[0];  // [B, T, F]
    const float* Rm   = (const float*)d_in[1];  // [F, U]
    const float* Wm   = (const float*)d_in[2];  // [U, U]
    const float* bias = (const float*)d_in[3];  // [U]
    const float* x0   = (const float*)d_in[4];  // [U]
    float* out = (float*)d_out;                 // [T, B, U]

    const size_t hElems = (size_t)T * B * U;
    dim3 pgrid(T / 64, U / 64, B);

    if (ws_size >= hElems * sizeof(float)) {
        float* h = (float*)d_ws;
        proj_kernel<float><<<pgrid, 512, 0, stream>>>(in, Rm, h);
        rnn_kernel<float><<<dim3(B), 512, 0, stream>>>(h, Wm, bias, x0, out);
    } else {
        __hip_bfloat16* h = (__hip_bfloat16*)d_ws;
        proj_kernel<__hip_bfloat16><<<pgrid, 512, 0, stream>>>(in, Rm, h);
        rnn_kernel<__hip_bfloat16><<<dim3(B), 512, 0, stream>>>(h, Wm, bias, x0, out);
    }
}

// Round 3
// 674.102 us; speedup vs baseline: 3.3196x; 1.9169x over previous
//
#include <hip/hip_runtime.h>
#include <hip/hip_bf16.h>

// Problem constants (BasicRecurrentLayer): B=64, T=1024, F=128, U=256
constexpr int B = 64;
constexpr int T = 1024;
constexpr int F = 128;
constexpr int U = 256;
constexpr int CH = 8;       // rnn: steps per h-prefetch/out-flush chunk

// ---------------------------------------------------------------------------
// h storage helpers (fp32 if workspace fits 64 MB, else bf16 = 32 MB)
// ---------------------------------------------------------------------------
__device__ __forceinline__ float toF32(float v) { return v; }
__device__ __forceinline__ float toF32(__hip_bfloat16 v) { return __bfloat162float(v); }

__device__ __forceinline__ void store8(float* p, const float* a) {
    ((float4*)p)[0] = make_float4(a[0], a[1], a[2], a[3]);
    ((float4*)p)[1] = make_float4(a[4], a[5], a[6], a[7]);
}
__device__ __forceinline__ void store8(__hip_bfloat16* p, const float* a) {
    unsigned int v[4];
    #pragma unroll
    for (int i = 0; i < 4; ++i) {
        __hip_bfloat16 lo = __float2bfloat16(a[2 * i]);
        __hip_bfloat16 hi = __float2bfloat16(a[2 * i + 1]);
        unsigned short lob = *(unsigned short*)&lo;
        unsigned short hib = *(unsigned short*)&hi;
        v[i] = (unsigned int)lob | ((unsigned int)hib << 16);
    }
    ((uint4*)p)[0] = make_uint4(v[0], v[1], v[2], v[3]);
}

__device__ __forceinline__ float rdlane(float v, int l) {
    return __uint_as_float(__builtin_amdgcn_readlane(__float_as_uint(v), l));
}

// Exact identity tanh(x) = 1 - 2/(1+e^{2x}); e^{2x} = exp2(x*2*log2(e)).
// v_exp_f32 + v_rcp_f32, ~1e-6 abs err, correct saturation at +-1, no branches.
__device__ __forceinline__ float tanh_fast(float x) {
    float e = __builtin_amdgcn_exp2f(x * 2.885390081777927f);
    float r = __builtin_amdgcn_rcpf(1.0f + e);
    return fmaf(-2.0f, r, 1.0f);
}

// lgkmcnt(0) only (vmcnt=63, expcnt=7 -> no wait): 0xC07F. Raw barrier that
// does NOT drain vmcnt, so h-prefetch / out-stores stay in flight across it.
__device__ __forceinline__ void lds_barrier() {
    __builtin_amdgcn_s_waitcnt(0xC07F);
    asm volatile("" ::: "memory");
    __builtin_amdgcn_s_barrier();
    asm volatile("" ::: "memory");
}

// ---------------------------------------------------------------------------
// Kernel 1: projection  h[t, b, u] = sum_f inputs[b, t, f] * R[f, u]
// Grid (T/64, U/64, B), 512 threads (8 waves). lane = t-row r; wave owns 8 u.
// A-tile (64x128 fp32, 32 KB) in LDS, XOR-swizzled float4 slots (conflict-
// free b128 read+write). R comes in as wave-uniform scalar loads (SGPRs),
// ping-pong prefetched one k4-group ahead to hide s_load latency.
// ---------------------------------------------------------------------------
template <typename HT>
__global__ __launch_bounds__(512, 2) void proj_kernel(
    const float* __restrict__ in,   // [B, T, F]
    const float* __restrict__ Rm,   // [F, U]
    HT* __restrict__ h)             // [T, B, U]
{
    const int t0   = blockIdx.x * 64;
    const int u0b  = blockIdx.y * 64;
    const int b    = blockIdx.z;
    const int tid  = threadIdx.x;
    const int lane = tid & 63;      // = r (t-row within tile)
    const int wv   = tid >> 6;      // 0..7
    const int u0   = __builtin_amdgcn_readfirstlane(u0b + wv * 8);

    __shared__ float4 a4[64 * 32];  // 32 KB, swizzled

    const float4* src = (const float4*)(in + ((size_t)b * T + t0) * F);
    #pragma unroll
    for (int it = 0; it < 4; ++it) {
        int f  = tid + it * 512;        // 0..2047 coalesced
        int r  = f >> 5;
        int k4 = f & 31;
        a4[(r << 5) | (k4 ^ (r & 31))] = src[f];
    }
    __syncthreads();

    const float* Rp = Rm + u0;      // wave-uniform -> scalar loads
    float acc[8];
    #pragma unroll
    for (int j = 0; j < 8; ++j) acc[j] = 0.f;

    float ra[32], rb[32];           // uniform (SGPR) ping-pong R buffers
    #pragma unroll
    for (int kk = 0; kk < 4; ++kk)
        #pragma unroll
        for (int j = 0; j < 8; ++j)
            ra[kk * 8 + j] = Rp[(size_t)kk * U + j];

    const int r = lane;
    #pragma unroll
    for (int k4 = 0; k4 < 32; k4 += 2) {
        // prefetch k4+1 into rb
        #pragma unroll
        for (int kk = 0; kk < 4; ++kk)
            #pragma unroll
            for (int j = 0; j < 8; ++j)
                rb[kk * 8 + j] = Rp[(size_t)((k4 + 1) * 4 + kk) * U + j];

        float4 av = a4[(r << 5) | (k4 ^ (r & 31))];
        #pragma unroll
        for (int j = 0; j < 8; ++j) {
            acc[j] = fmaf(av.x, ra[0 * 8 + j], acc[j]);
            acc[j] = fmaf(av.y, ra[1 * 8 + j], acc[j]);
            acc[j] = fmaf(av.z, ra[2 * 8 + j], acc[j]);
            acc[j] = fmaf(av.w, ra[3 * 8 + j], acc[j]);
        }

        // prefetch k4+2 into ra
        if (k4 + 2 < 32) {
            #pragma unroll
            for (int kk = 0; kk < 4; ++kk)
                #pragma unroll
                for (int j = 0; j < 8; ++j)
                    ra[kk * 8 + j] = Rp[(size_t)((k4 + 2) * 4 + kk) * U + j];
        }

        float4 av2 = a4[(r << 5) | ((k4 + 1) ^ (r & 31))];
        #pragma unroll
        for (int j = 0; j < 8; ++j) {
            acc[j] = fmaf(av2.x, rb[0 * 8 + j], acc[j]);
            acc[j] = fmaf(av2.y, rb[1 * 8 + j], acc[j]);
            acc[j] = fmaf(av2.z, rb[2 * 8 + j], acc[j]);
            acc[j] = fmaf(av2.w, rb[3 * 8 + j], acc[j]);
        }
    }

    HT* hp = h + ((size_t)(t0 + r) * B + b) * U + u0;
    store8(hp, acc);
}

// ---------------------------------------------------------------------------
// Kernel 2: recurrence. Grid 64 (one WG per batch row), 512 threads = 8 waves.
// Wave wv owns k-range [32wv, 32wv+32) AND reduces u' range [32wv, 32wv+32).
// Lane l owns u' columns {4l..4l+3} for the partial GEMV:
//   W regs: w{0..3}[kk] = W[32wv+kk][4l+{0..3}]  (128 floats, arch VGPRs —
//   launch_bounds(512,2) caps unified budget at 256 so no AGPR round-trip).
// Per step: 32 v_readlane (k-broadcast, SGPRs) + 128 v_fma, 1 ds_write_b128
// of partials, ONE raw barrier, 8 ds_read_b32 partial reduction + tanh.
// The reduced value tv sits in this wave's own lanes 0..31 — it IS next
// step's readlane source, so no state write-back and no second barrier.
// Partials double-buffered (parity i&1) to make one barrier race-free.
// ---------------------------------------------------------------------------
template <typename HT>
__global__ __launch_bounds__(512, 2) void rnn_kernel(
    const HT* __restrict__ h,        // [T, B, U]
    const float* __restrict__ Wm,    // [U, U]
    const float* __restrict__ bias,  // [U]
    const float* __restrict__ x0,    // [U]
    float* __restrict__ out)         // [T, B, U]
{
    const int b    = blockIdx.x;
    const int tid  = threadIdx.x;
    const int l    = tid & 63;
    const int wv   = tid >> 6;       // 0..7
    const int k0   = wv << 5;        // wave's k-range / u'-reduction base

    __shared__ float p[2][8][256];   // 16 KB partials, double-buffered

    // W columns: w{j}[kk] = W[k0+kk][4l+j] — float4 loads, coalesced.
    float w0[32], w1[32], w2[32], w3[32];
    {
        const float* wp = Wm + (size_t)k0 * U + 4 * l;
        #pragma unroll
        for (int kk = 0; kk < 32; ++kk) {
            float4 v = *(const float4*)(wp + (size_t)kk * U);
            w0[kk] = v.x; w1[kk] = v.y; w2[kk] = v.z; w3[kk] = v.w;
        }
    }

    const bool act = (l < 32);
    const int  u   = k0 + (l & 31);  // dup for lanes 32..63 (harmless)
    const float bv = bias[u];

    float tv = x0[u];                // s_new[k0 + (l&31)] lives here each step

    const size_t sT = (size_t)B * U;
    const HT* hp = h + (size_t)b * U + u;
    float* op = out + (size_t)b * U + u;

    float hc[CH], hn[CH], ob[CH];
    #pragma unroll
    for (int i = 0; i < CH; ++i) hc[i] = toF32(hp[(size_t)i * sT]);

    for (int tc = 0; tc < T; tc += CH) {
        // prefetch next chunk's h (not drained at raw barriers)
        if (tc + CH < T) {
            #pragma unroll
            for (int i = 0; i < CH; ++i)
                hn[i] = toF32(hp[(size_t)(tc + CH + i) * sT]);
        }
        // flush previous chunk's outputs
        if (tc > 0 && act) {
            #pragma unroll
            for (int i = 0; i < CH; ++i)
                op[(size_t)(tc - CH + i) * sT] = ob[i];
        }

        #pragma unroll
        for (int i = 0; i < CH; ++i) {
            // broadcast this wave's 32 state values into SGPRs
            float sb[32];
            #pragma unroll
            for (int kk = 0; kk < 32; ++kk) sb[kk] = rdlane(tv, kk);

            float a0 = 0.f, a1 = 0.f, a2 = 0.f, a3 = 0.f;
            #pragma unroll
            for (int kk = 0; kk < 32; ++kk) {
                a0 = fmaf(sb[kk], w0[kk], a0);
                a1 = fmaf(sb[kk], w1[kk], a1);
                a2 = fmaf(sb[kk], w2[kk], a2);
                a3 = fmaf(sb[kk], w3[kk], a3);
            }
            *(float4*)&p[i & 1][wv][4 * l] = make_float4(a0, a1, a2, a3);

            lds_barrier();           // ONE barrier per step (lgkm only)

            // reduce 8 partials for u' = k0 + (l&31); lanes 32..63 duplicate
            // (same-address LDS reads broadcast — no conflict)
            float red = p[i & 1][0][u];
            #pragma unroll
            for (int w2i = 1; w2i < 8; ++w2i) red += p[i & 1][w2i][u];

            float val = tanh_fast(red + hc[i] + bv);
            ob[i] = val;
            tv = val;                // next step's readlane source
        }

        if (tc + CH < T) {
            #pragma unroll
            for (int i = 0; i < CH; ++i) hc[i] = hn[i];
        }
    }

    if (act) {
        #pragma unroll
        for (int i = 0; i < CH; ++i)
            op[(size_t)(T - CH + i) * sT] = ob[i];
    }
}

// ---------------------------------------------------------------------------
extern "C" void kernel_launch(void* const* d_in, const int* in_sizes, int n_in,
                              void* d_out, int out_size, void* d_ws, size_t ws_size,
                              hipStream_t stream) {
    const float* in   = (const float*)d_in[0];  // [B, T, F]
    const float* Rm   = (const float*)d_in[1];  // [F, U]
    const float* Wm   = (const float*)d_in[2];  // [U, U]
    const float* bias = (const float*)d_in[3];  // [U]
    const float* x0   = (const float*)d_in[4];  // [U]
    float* out = (float*)d_out;                 // [T, B, U]

    const size_t hElems = (size_t)T * B * U;
    dim3 pgrid(T / 64, U / 64, B);

    if (ws_size >= hElems * sizeof(float)) {
        float* h = (float*)d_ws;
        proj_kernel<float><<<pgrid, 512, 0, stream>>>(in, Rm, h);
        rnn_kernel<float><<<dim3(B), 512, 0, stream>>>(h, Wm, bias, x0, out);
    } else {
        __hip_bfloat16* h = (__hip_bfloat16*)d_ws;
        proj_kernel<__hip_bfloat16><<<pgrid, 512, 0, stream>>>(in, Rm, h);
        rnn_kernel<__hip_bfloat16><<<dim3(B), 512, 0, stream>>>(h, Wm, bias, x0, out);
    }
}